// Round 12
// baseline (1379.030 us; speedup 1.0000x reference)
//
#include <hip/hip_runtime.h>
#include <math.h>

// N=16384, IN=512, HID=256, E=262144.
// Z = adj @ (X@W), both GEMMs via fp16 split-2 MFMA (a=a1+a2, b=b1+b2;
// products a1b1+a1b2+a2b1). LDS-free, barrier-free fragment-direct scheme.
// R12: splitK=4 -> grid 512 = 2 blocks/CU = 16 waves/CU (every prior round
// ran at 8 waves/CU -- first real TLP increase). No extra partial buffers:
// Z is pre-zeroed and all 4 z-blocks atomicAdd their accS (4 unordered f32
// adds/element, rounding ~1e-5). launch_bounds(512,4) pins VGPR<=128.

typedef _Float16 half8v __attribute__((ext_vector_type(8)));
typedef __fp16   fp16x2 __attribute__((ext_vector_type(2)));
typedef __attribute__((ext_vector_type(4))) float floatx4;

#define NM_ (16384L * 256L)

// ---- RNE split (prep kernels; exact residual in f32) ----
static __device__ __forceinline__ void split2_pair_f16(float x0, float x1,
                                                       unsigned& q1, unsigned& q2) {
  _Float16 h0 = (_Float16)x0, h1 = (_Float16)x1;
  float r0 = x0 - (float)h0, r1 = x1 - (float)h1;
  _Float16 g0 = (_Float16)r0, g1 = (_Float16)r1;
  q1 = ((unsigned)__builtin_bit_cast(unsigned short, h1) << 16) |
       __builtin_bit_cast(unsigned short, h0);
  q2 = ((unsigned)__builtin_bit_cast(unsigned short, g1) << 16) |
       __builtin_bit_cast(unsigned short, g0);
}

// ---- RTZ in-register split: 8 f32 -> (a0, a1) fp16 ----
static __device__ __forceinline__ void split8(const float* __restrict__ x,
                                              half8v& a0, half8v& a1) {
  union U { unsigned u[4]; half8v h; } u0, u1;
#pragma unroll
  for (int p = 0; p < 4; ++p) {
    fp16x2 h = __builtin_amdgcn_cvt_pkrtz(x[2 * p], x[2 * p + 1]);
    float r0 = x[2 * p]     - (float)h[0];   // exact
    float r1 = x[2 * p + 1] - (float)h[1];
    fp16x2 g = __builtin_amdgcn_cvt_pkrtz(r0, r1);
    u0.u[p] = __builtin_bit_cast(unsigned, h);
    u1.u[p] = __builtin_bit_cast(unsigned, g);
  }
  a0 = u0.h; a1 = u1.h;
}

// ---- W[512][256] -> fragment-ready split WT: [s][kt(16)][c(4)][n(256)][8] ----
__global__ __launch_bounds__(256)
void w_split(const float* __restrict__ W, unsigned short* __restrict__ WT)
{
  const int b  = blockIdx.x;          // 64 blocks
  const int kt = b >> 2, c = b & 3;
  const int n  = threadIdx.x;
  const int k0 = kt * 32 + c * 8;
  float x[8];
#pragma unroll
  for (int j = 0; j < 8; ++j) x[j] = W[(k0 + j) * 256 + n];
  unsigned q1[4], q2[4];
#pragma unroll
  for (int p = 0; p < 4; ++p)
    split2_pair_f16(x[2 * p], x[2 * p + 1], q1[p], q2[p]);
  const long o = ((long)(kt * 4 + c) * 256 + n) * 8;
  *(uint4*)&WT[o]          = make_uint4(q1[0], q1[1], q1[2], q1[3]);
  *(uint4*)&WT[o + 131072] = make_uint4(q2[0], q2[1], q2[2], q2[3]);
}

// ---- GEMM1: XW = X @ W, LDS-free fragment-direct, chunk-4 accS ----
__global__ __launch_bounds__(256, 2)
void gemm_xw(const float* __restrict__ X, const unsigned short* __restrict__ WT,
             float* __restrict__ XW)
{
  const int tid  = threadIdx.x;
  const int lane = tid & 63;
  const int w    = tid >> 6;
  const int wm = w >> 1, wn = w & 1;
  const long m0 = (long)(blockIdx.x >> 1) * 128;
  const long n0 = (long)(blockIdx.x & 1) * 128;
  const int fr = lane & 15, kc = lane >> 4;

  const unsigned short* Bq = WT + (long)kc * 2048 + ((long)n0 + wn * 64 + fr) * 8;

  const float* ap[4];
#pragma unroll
  for (int fm = 0; fm < 4; ++fm)
    ap[fm] = X + (m0 + wm * 64 + fm * 16 + fr) * 512L + kc * 8;

  floatx4 acc[4][4], accS[4][4];
#pragma unroll
  for (int i = 0; i < 4; ++i)
#pragma unroll
    for (int j = 0; j < 4; ++j) { acc[i][j] = (floatx4)0.f; accS[i][j] = (floatx4)0.f; }

  for (int t = 0; t < 16; ++t) {
    half8v bf0[4], bf1[4];
#pragma unroll
    for (int fn = 0; fn < 4; ++fn) {
      bf0[fn] = *(const half8v*)(Bq + (long)t * 8192 + fn * 128);
      bf1[fn] = *(const half8v*)(Bq + (long)t * 8192 + fn * 128 + 131072);
    }
#pragma unroll
    for (int fm = 0; fm < 4; ++fm) {
      float x[8];
      *(float4*)&x[0] = *(const float4*)(ap[fm] + t * 32);
      *(float4*)&x[4] = *(const float4*)(ap[fm] + t * 32 + 4);
      half8v a0, a1;
      split8(x, a0, a1);
#pragma unroll
      for (int fn = 0; fn < 4; ++fn) {
        floatx4 d = acc[fm][fn];
        d = __builtin_amdgcn_mfma_f32_16x16x32_f16(a0, bf0[fn], d, 0, 0, 0);
        d = __builtin_amdgcn_mfma_f32_16x16x32_f16(a0, bf1[fn], d, 0, 0, 0);
        d = __builtin_amdgcn_mfma_f32_16x16x32_f16(a1, bf0[fn], d, 0, 0, 0);
        acc[fm][fn] = d;
      }
    }
    if ((t & 3) == 3) {   // chunk-4 flush: shortens fp32 chain at large |acc|
#pragma unroll
      for (int i = 0; i < 4; ++i)
#pragma unroll
        for (int j = 0; j < 4; ++j) { accS[i][j] += acc[i][j]; acc[i][j] = (floatx4)0.f; }
    }
  }
#pragma unroll
  for (int fm = 0; fm < 4; ++fm)
#pragma unroll
    for (int fn = 0; fn < 4; ++fn) {
      const long col  = n0 + wn * 64 + fn * 16 + fr;
      const long rowb = m0 + wm * 64 + fm * 16 + kc * 4;
#pragma unroll
      for (int j = 0; j < 4; ++j)
        XW[(rowb + j) * 256 + col] = accS[fm][fn][j];
    }
}

// ---- transpose + split2 XW -> fragment-ready: [s][kt(512)][c(4)][n(256)][8] ----
__global__ __launch_bounds__(256)
void transpose_split(const float* __restrict__ XW,
                     unsigned short* __restrict__ X1,
                     unsigned short* __restrict__ X2)
{
  __shared__ float T[64][65];
  const int tid = threadIdx.x;
  const long kb = (long)blockIdx.x * 64;   // XW row (k) tile
  const long nb = (long)blockIdx.y * 64;   // XW col (n) tile

#pragma unroll
  for (int i = 0; i < 4; ++i) {
    int idx = tid + 256 * i;
    int r = idx >> 4, c4 = (idx & 15) * 4;
    float4 v = *(const float4*)&XW[(kb + r) * 256 + nb + c4];
    T[r][c4 + 0] = v.x; T[r][c4 + 1] = v.y; T[r][c4 + 2] = v.z; T[r][c4 + 3] = v.w;
  }
  __syncthreads();

#pragma unroll
  for (int i = 0; i < 2; ++i) {
    int idx = tid + 256 * i;
    int n = idx >> 3, kq = (idx & 7) * 8;
    float x[8];
#pragma unroll
    for (int j = 0; j < 8; ++j) x[j] = T[kq + j][n];
    unsigned q1[4], q2[4];
#pragma unroll
    for (int p = 0; p < 4; ++p)
      split2_pair_f16(x[2 * p], x[2 * p + 1], q1[p], q2[p]);
    const long gk = kb + kq;
    const long gt = gk >> 5;
    const int  c  = (int)((gk >> 3) & 3);
    const long o  = ((gt * 4 + c) * 256 + (nb + n)) * 8;
    *(uint4*)&X1[o] = make_uint4(q1[0], q1[1], q1[2], q1[3]);
    *(uint4*)&X2[o] = make_uint4(q2[0], q2[1], q2[2], q2[3]);
  }
}

// ---- zero-fill Z (must run every launch; harness poisons ws once) ----
__global__ __launch_bounds__(256)
void zero_fill(float* __restrict__ Z, long n4)
{
  long i = (long)blockIdx.x * 256 + threadIdx.x;
  const long stride = (long)gridDim.x * 256;
  float4 zv; zv.x = zv.y = zv.z = zv.w = 0.f;
  for (; i < n4; i += stride) ((float4*)Z)[i] = zv;
}

// ---- GEMM2: Z += adj @ XW (atomic combine). LDS-free, barrier-free. ----
// 512 thr = 8 waves (2m x 4n), BM=128 BN=256, splitK=4 -> grid 512 =
// 2 blocks/CU = 16 waves/CU. adj read exactly once (z-quarters disjoint).
__global__ __launch_bounds__(512, 4)
void gemm_adj(const float* __restrict__ A, const unsigned short* __restrict__ Bg,
              float* __restrict__ Z)
{
  const int tid  = threadIdx.x;
  const int lane = tid & 63;
  const int w    = tid >> 6;          // 0..7
  const int wm = w >> 2, wn = w & 3;
  const int bid = blockIdx.x;
  const long m0 = (long)(bid & 127) * 128;
  const int  z  = bid >> 7;           // 0..3, K-quarter
  const int fr = lane & 15, kc = lane >> 4;

  // B base for this z-quarter: quarter = 128 k-tiles x 8192 ushorts
  const unsigned short* Bq0 = Bg + (long)z * 1048576 + (long)kc * 2048 +
                              ((long)wn * 64 + fr) * 8;
  const unsigned short* Bq1 = Bq0 + NM_;

  const float* ap[4];
#pragma unroll
  for (int fm = 0; fm < 4; ++fm)
    ap[fm] = A + (m0 + wm * 64 + fm * 16 + fr) * 16384L + (long)z * 4096 + kc * 8;

  floatx4 acc[4][4], accS[4][4];
#pragma unroll
  for (int i = 0; i < 4; ++i)
#pragma unroll
    for (int j = 0; j < 4; ++j) { acc[i][j] = (floatx4)0.f; accS[i][j] = (floatx4)0.f; }

  float  ra[4][8];     // raw A(t) per fm
  half8v bf0[4], bf1[4];

  // prologue: tile 0
#pragma unroll
  for (int fm = 0; fm < 4; ++fm) {
    *(float4*)&ra[fm][0] = *(const float4*)(ap[fm]);
    *(float4*)&ra[fm][4] = *(const float4*)(ap[fm] + 4);
  }
#pragma unroll
  for (int fn = 0; fn < 4; ++fn) {
    bf0[fn] = *(const half8v*)(Bq0 + fn * 128);
    bf1[fn] = *(const half8v*)(Bq1 + fn * 128);
  }

  for (int t = 0; t < 128; ++t) {
    const long ko = (long)((t + 1) & 127) * 32;     // next-tile A offset (wraps)
    const long bo = (long)((t + 1) & 127) * 8192;   // next-tile B offset
#pragma unroll
    for (int fm = 0; fm < 4; ++fm) {
      half8v a0, a1;
      split8(ra[fm], a0, a1);
      // reload ra[fm] for t+1 (regs free after split; ~1 iter of cover)
      *(float4*)&ra[fm][0] = *(const float4*)(ap[fm] + ko);
      *(float4*)&ra[fm][4] = *(const float4*)(ap[fm] + ko + 4);
#pragma unroll
      for (int fn = 0; fn < 4; ++fn) {
        floatx4 d = acc[fm][fn];
        d = __builtin_amdgcn_mfma_f32_16x16x32_f16(a0, bf0[fn], d, 0, 0, 0);
        d = __builtin_amdgcn_mfma_f32_16x16x32_f16(a0, bf1[fn], d, 0, 0, 0);
        d = __builtin_amdgcn_mfma_f32_16x16x32_f16(a1, bf0[fn], d, 0, 0, 0);
        acc[fm][fn] = d;
      }
    }
#pragma unroll
    for (int fn = 0; fn < 4; ++fn) {
      bf0[fn] = *(const half8v*)(Bq0 + bo + fn * 128);
      bf1[fn] = *(const half8v*)(Bq1 + bo + fn * 128);
    }
    if ((t & 31) == 31) {   // chunked accumulation (numerics, as R4-R11)
#pragma unroll
      for (int i = 0; i < 4; ++i)
#pragma unroll
        for (int j = 0; j < 4; ++j) { accS[i][j] += acc[i][j]; acc[i][j] = (floatx4)0.f; }
    }
  }

  // epilogue: atomic combine (4 z-blocks per element, unordered f32 adds)
  // C/D layout col=lane&15, row=kc*4+j
#pragma unroll
  for (int fm = 0; fm < 4; ++fm)
#pragma unroll
    for (int fn = 0; fn < 4; ++fn) {
      const long col  = wn * 64 + fn * 16 + fr;
      const long rowb = m0 + wm * 64 + fm * 16 + kc * 4;
#pragma unroll
      for (int j = 0; j < 4; ++j)
        atomicAdd(&Z[(rowb + j) * 256 + col], accS[fm][fn][j]);
    }
}

// ---------------- edge scoring ----------------
__global__ __launch_bounds__(256)
void edge_score(const float* __restrict__ Z, const float* __restrict__ w2,
                const int* __restrict__ te, const int* __restrict__ fe,
                int E, float* __restrict__ out)
{
  const long gtid = (long)blockIdx.x * 256 + threadIdx.x;
  const long wid = gtid >> 6;
  const int lane = threadIdx.x & 63;
  if (wid >= 2L * E) return;
  const int* ep = (wid < E) ? (te + 2 * wid) : (fe + 2 * (wid - E));
  const int src = ep[0];
  const int dst = ep[1];
  const float4 a = ((const float4*)(Z + (long)src * 256))[lane];
  const float4 b = ((const float4*)(Z + (long)dst * 256))[lane];
  const float4 w = ((const float4*)w2)[lane];
  float s = a.x * b.x * w.x + a.y * b.y * w.y + a.z * b.z * w.z + a.w * b.w * w.w;
#pragma unroll
  for (int off = 32; off > 0; off >>= 1) s += __shfl_down(s, off);
  if (lane == 0) out[wid] = 1.0f / (1.0f + expf(-s));
}

extern "C" void kernel_launch(void* const* d_in, const int* in_sizes, int n_in,
                              void* d_out, int out_size, void* d_ws, size_t ws_size,
                              hipStream_t stream)
{
  const float* X   = (const float*)d_in[0];
  const float* adj = (const float*)d_in[1];
  const float* W   = (const float*)d_in[2];
  const float* W2  = (const float*)d_in[3];
  const int*   te  = (const int*)d_in[4];
  const int*   fe  = (const int*)d_in[5];

  const int E = in_sizes[4] / 2;

  float* ws = (float*)d_ws;
  float* Z  = ws;                      // XW first (dead after transpose_split),
                                       // then zero-filled and used as Z
  unsigned short* X1 = (unsigned short*)(ws + NM_);
  unsigned short* X2 = X1 + NM_;
  unsigned short* WT = X2 + NM_;       // 0.5 MB
  // total ws: NM*4 + 2*NM*2 + 0.5MB ~ 34.1 MB

  dim3 b256(256);
  w_split<<<dim3(64), b256, 0, stream>>>(W, WT);
  gemm_xw<<<dim3(256), b256, 0, stream>>>(X, WT, Z);           // XW -> Z slot
  transpose_split<<<dim3(256, 4), b256, 0, stream>>>(Z, X1, X2);
  zero_fill<<<dim3(1024), b256, 0, stream>>>(Z, NM_ / 4);
  gemm_adj<<<dim3(512), dim3(512), 0, stream>>>(adj, X1, Z);
  const long nwaves = 2L * E;
  const int nblocks = (int)((nwaves + 3) / 4);
  edge_score<<<dim3(nblocks), b256, 0, stream>>>(Z, W2, te, fe, E, (float*)d_out);
}

// Round 13
// 1262.697 us; speedup vs baseline: 1.0921x; 1.0921x over previous
//
#include <hip/hip_runtime.h>
#include <math.h>

// N=16384, IN=512, HID=256, E=262144.
// Z = adj @ (X@W), both GEMMs via fp16 split-2 MFMA (a=a1+a2, b=b1+b2;
// products a1b1+a1b2+a2b1). LDS-free, barrier-free fragment-direct scheme.
// R13: clean 16 waves/CU -- BN=128 doubles grid to 512 (8-wave blocks,
// wave=64x32, ~110 VGPR so 2 blocks/CU co-schedule), splitK=2, 2 partials,
// no atomics. Pair-swizzle puts both n-halves of an (m,z) adj panel on the
// same XCD 8 slots apart -> adj fetched from HBM once, shared via L2.

typedef _Float16 half8v __attribute__((ext_vector_type(8)));
typedef __fp16   fp16x2 __attribute__((ext_vector_type(2)));
typedef __attribute__((ext_vector_type(4))) float floatx4;

#define NM_ (16384L * 256L)

// ---- RNE split (prep kernels; exact residual in f32) ----
static __device__ __forceinline__ void split2_pair_f16(float x0, float x1,
                                                       unsigned& q1, unsigned& q2) {
  _Float16 h0 = (_Float16)x0, h1 = (_Float16)x1;
  float r0 = x0 - (float)h0, r1 = x1 - (float)h1;
  _Float16 g0 = (_Float16)r0, g1 = (_Float16)r1;
  q1 = ((unsigned)__builtin_bit_cast(unsigned short, h1) << 16) |
       __builtin_bit_cast(unsigned short, h0);
  q2 = ((unsigned)__builtin_bit_cast(unsigned short, g1) << 16) |
       __builtin_bit_cast(unsigned short, g0);
}

// ---- RTZ in-register split: 8 f32 -> (a0, a1) fp16 ----
static __device__ __forceinline__ void split8(const float* __restrict__ x,
                                              half8v& a0, half8v& a1) {
  union U { unsigned u[4]; half8v h; } u0, u1;
#pragma unroll
  for (int p = 0; p < 4; ++p) {
    fp16x2 h = __builtin_amdgcn_cvt_pkrtz(x[2 * p], x[2 * p + 1]);
    float r0 = x[2 * p]     - (float)h[0];   // exact
    float r1 = x[2 * p + 1] - (float)h[1];
    fp16x2 g = __builtin_amdgcn_cvt_pkrtz(r0, r1);
    u0.u[p] = __builtin_bit_cast(unsigned, h);
    u1.u[p] = __builtin_bit_cast(unsigned, g);
  }
  a0 = u0.h; a1 = u1.h;
}

// ---- W[512][256] -> fragment-ready split WT: [s][kt(16)][c(4)][n(256)][8] ----
__global__ __launch_bounds__(256)
void w_split(const float* __restrict__ W, unsigned short* __restrict__ WT)
{
  const int b  = blockIdx.x;          // 64 blocks
  const int kt = b >> 2, c = b & 3;
  const int n  = threadIdx.x;
  const int k0 = kt * 32 + c * 8;
  float x[8];
#pragma unroll
  for (int j = 0; j < 8; ++j) x[j] = W[(k0 + j) * 256 + n];
  unsigned q1[4], q2[4];
#pragma unroll
  for (int p = 0; p < 4; ++p)
    split2_pair_f16(x[2 * p], x[2 * p + 1], q1[p], q2[p]);
  const long o = ((long)(kt * 4 + c) * 256 + n) * 8;
  *(uint4*)&WT[o]          = make_uint4(q1[0], q1[1], q1[2], q1[3]);
  *(uint4*)&WT[o + 131072] = make_uint4(q2[0], q2[1], q2[2], q2[3]);
}

// ---- GEMM1: XW = X @ W, LDS-free fragment-direct, chunk-4 accS ----
__global__ __launch_bounds__(256, 2)
void gemm_xw(const float* __restrict__ X, const unsigned short* __restrict__ WT,
             float* __restrict__ XW)
{
  const int tid  = threadIdx.x;
  const int lane = tid & 63;
  const int w    = tid >> 6;
  const int wm = w >> 1, wn = w & 1;
  const long m0 = (long)(blockIdx.x >> 1) * 128;
  const long n0 = (long)(blockIdx.x & 1) * 128;
  const int fr = lane & 15, kc = lane >> 4;

  const unsigned short* Bq = WT + (long)kc * 2048 + ((long)n0 + wn * 64 + fr) * 8;

  const float* ap[4];
#pragma unroll
  for (int fm = 0; fm < 4; ++fm)
    ap[fm] = X + (m0 + wm * 64 + fm * 16 + fr) * 512L + kc * 8;

  floatx4 acc[4][4], accS[4][4];
#pragma unroll
  for (int i = 0; i < 4; ++i)
#pragma unroll
    for (int j = 0; j < 4; ++j) { acc[i][j] = (floatx4)0.f; accS[i][j] = (floatx4)0.f; }

  for (int t = 0; t < 16; ++t) {
    half8v bf0[4], bf1[4];
#pragma unroll
    for (int fn = 0; fn < 4; ++fn) {
      bf0[fn] = *(const half8v*)(Bq + (long)t * 8192 + fn * 128);
      bf1[fn] = *(const half8v*)(Bq + (long)t * 8192 + fn * 128 + 131072);
    }
#pragma unroll
    for (int fm = 0; fm < 4; ++fm) {
      float x[8];
      *(float4*)&x[0] = *(const float4*)(ap[fm] + t * 32);
      *(float4*)&x[4] = *(const float4*)(ap[fm] + t * 32 + 4);
      half8v a0, a1;
      split8(x, a0, a1);
#pragma unroll
      for (int fn = 0; fn < 4; ++fn) {
        floatx4 d = acc[fm][fn];
        d = __builtin_amdgcn_mfma_f32_16x16x32_f16(a0, bf0[fn], d, 0, 0, 0);
        d = __builtin_amdgcn_mfma_f32_16x16x32_f16(a0, bf1[fn], d, 0, 0, 0);
        d = __builtin_amdgcn_mfma_f32_16x16x32_f16(a1, bf0[fn], d, 0, 0, 0);
        acc[fm][fn] = d;
      }
    }
    if ((t & 3) == 3) {   // chunk-4 flush: shortens fp32 chain at large |acc|
#pragma unroll
      for (int i = 0; i < 4; ++i)
#pragma unroll
        for (int j = 0; j < 4; ++j) { accS[i][j] += acc[i][j]; acc[i][j] = (floatx4)0.f; }
    }
  }
#pragma unroll
  for (int fm = 0; fm < 4; ++fm)
#pragma unroll
    for (int fn = 0; fn < 4; ++fn) {
      const long col  = n0 + wn * 64 + fn * 16 + fr;
      const long rowb = m0 + wm * 64 + fm * 16 + kc * 4;
#pragma unroll
      for (int j = 0; j < 4; ++j)
        XW[(rowb + j) * 256 + col] = accS[fm][fn][j];
    }
}

// ---- transpose + split2 XW -> fragment-ready: [s][kt(512)][c(4)][n(256)][8] ----
__global__ __launch_bounds__(256)
void transpose_split(const float* __restrict__ XW,
                     unsigned short* __restrict__ X1,
                     unsigned short* __restrict__ X2)
{
  __shared__ float T[64][65];
  const int tid = threadIdx.x;
  const long kb = (long)blockIdx.x * 64;   // XW row (k) tile
  const long nb = (long)blockIdx.y * 64;   // XW col (n) tile

#pragma unroll
  for (int i = 0; i < 4; ++i) {
    int idx = tid + 256 * i;
    int r = idx >> 4, c4 = (idx & 15) * 4;
    float4 v = *(const float4*)&XW[(kb + r) * 256 + nb + c4];
    T[r][c4 + 0] = v.x; T[r][c4 + 1] = v.y; T[r][c4 + 2] = v.z; T[r][c4 + 3] = v.w;
  }
  __syncthreads();

#pragma unroll
  for (int i = 0; i < 2; ++i) {
    int idx = tid + 256 * i;
    int n = idx >> 3, kq = (idx & 7) * 8;
    float x[8];
#pragma unroll
    for (int j = 0; j < 8; ++j) x[j] = T[kq + j][n];
    unsigned q1[4], q2[4];
#pragma unroll
    for (int p = 0; p < 4; ++p)
      split2_pair_f16(x[2 * p], x[2 * p + 1], q1[p], q2[p]);
    const long gk = kb + kq;
    const long gt = gk >> 5;
    const int  c  = (int)((gk >> 3) & 3);
    const long o  = ((gt * 4 + c) * 256 + (nb + n)) * 8;
    *(uint4*)&X1[o] = make_uint4(q1[0], q1[1], q1[2], q1[3]);
    *(uint4*)&X2[o] = make_uint4(q2[0], q2[1], q2[2], q2[3]);
  }
}

// ---- GEMM2: Z-partials = adj @ XW. LDS-free, barrier-free, 16 waves/CU. ----
// 512 blocks x 512 thr (8 waves, 2m x 4n; wave = 64x32). BM=128, BN=128,
// splitK=2. Pair-swizzle: p = x + 8*(n + 2*y); x=XCD slot -> (m,z); the two
// n-halves of one (m,z) panel are 8 dispatch slots apart (same XCD).
__global__ __launch_bounds__(512)
void gemm_adj(const float* __restrict__ A, const unsigned short* __restrict__ Bg,
              float* __restrict__ P0, float* __restrict__ P1)
{
  const int tid  = threadIdx.x;
  const int lane = tid & 63;
  const int w    = tid >> 6;          // 0..7
  const int wm = w >> 2, wn = w & 3;
  const int p   = blockIdx.x;
  const int x   = p & 7;
  const int nh  = (p >> 3) & 1;       // n-half
  const int y   = p >> 4;             // 0..31
  const long m0 = (long)((y << 2) | (x >> 1)) * 128;
  const int  z  = x & 1;
  const long n0 = (long)nh * 128;
  float* __restrict__ Cp = z ? P1 : P0;
  const int fr = lane & 15, kc = lane >> 4;

  // B: [s][gt][c(4)][n(256)][8]; this wave's 32-col slice
  const unsigned short* Bq0 = Bg + (long)z * 2097152 + (long)kc * 2048 +
                              (n0 + wn * 32 + fr) * 8;
  const unsigned short* Bq1 = Bq0 + NM_;

  const float* ap[4];
#pragma unroll
  for (int fm = 0; fm < 4; ++fm)
    ap[fm] = A + (m0 + wm * 64 + fm * 16 + fr) * 16384L + (long)z * 8192 + kc * 8;

  floatx4 acc[4][2], accS[4][2];
#pragma unroll
  for (int i = 0; i < 4; ++i)
#pragma unroll
    for (int j = 0; j < 2; ++j) { acc[i][j] = (floatx4)0.f; accS[i][j] = (floatx4)0.f; }

  for (int t = 0; t < 256; ++t) {
    const long bo = (long)t * 8192;
    half8v bf0[2], bf1[2];
#pragma unroll
    for (int fn = 0; fn < 2; ++fn) {
      bf0[fn] = *(const half8v*)(Bq0 + bo + fn * 128);
      bf1[fn] = *(const half8v*)(Bq1 + bo + fn * 128);
    }
#pragma unroll
    for (int fm = 0; fm < 4; ++fm) {
      float xv[8];
      *(float4*)&xv[0] = *(const float4*)(ap[fm] + t * 32);
      *(float4*)&xv[4] = *(const float4*)(ap[fm] + t * 32 + 4);
      half8v a0, a1;
      split8(xv, a0, a1);
#pragma unroll
      for (int fn = 0; fn < 2; ++fn) {
        floatx4 d = acc[fm][fn];
        d = __builtin_amdgcn_mfma_f32_16x16x32_f16(a0, bf0[fn], d, 0, 0, 0);
        d = __builtin_amdgcn_mfma_f32_16x16x32_f16(a0, bf1[fn], d, 0, 0, 0);
        d = __builtin_amdgcn_mfma_f32_16x16x32_f16(a1, bf0[fn], d, 0, 0, 0);
        acc[fm][fn] = d;
      }
    }
    if ((t & 31) == 31) {   // chunked accumulation (numerics, as R4-R12)
#pragma unroll
      for (int i = 0; i < 4; ++i)
#pragma unroll
        for (int j = 0; j < 2; ++j) { accS[i][j] += acc[i][j]; acc[i][j] = (floatx4)0.f; }
    }
  }

  // epilogue: C/D layout col=lane&15, row=kc*4+j
#pragma unroll
  for (int fm = 0; fm < 4; ++fm)
#pragma unroll
    for (int fn = 0; fn < 2; ++fn) {
      const long col  = n0 + wn * 32 + fn * 16 + fr;
      const long rowb = m0 + wm * 64 + fm * 16 + kc * 4;
#pragma unroll
      for (int j = 0; j < 4; ++j)
        Cp[(rowb + j) * 256 + col] = accS[fm][fn][j];
    }
}

// ---------------- P1 += P0 ----------------
__global__ __launch_bounds__(256)
void reduce_add(const float* __restrict__ P0, float* __restrict__ P1, long n4)
{
  long i = (long)blockIdx.x * 256 + threadIdx.x;
  const long stride = (long)gridDim.x * 256;
  for (; i < n4; i += stride) {
    float4 a = ((const float4*)P0)[i];
    float4 b = ((const float4*)P1)[i];
    b.x += a.x; b.y += a.y; b.z += a.z; b.w += a.w;
    ((float4*)P1)[i] = b;
  }
}

// ---------------- edge scoring ----------------
__global__ __launch_bounds__(256)
void edge_score(const float* __restrict__ Z, const float* __restrict__ w2,
                const int* __restrict__ te, const int* __restrict__ fe,
                int E, float* __restrict__ out)
{
  const long gtid = (long)blockIdx.x * 256 + threadIdx.x;
  const long wid = gtid >> 6;
  const int lane = threadIdx.x & 63;
  if (wid >= 2L * E) return;
  const int* ep = (wid < E) ? (te + 2 * wid) : (fe + 2 * (wid - E));
  const int src = ep[0];
  const int dst = ep[1];
  const float4 a = ((const float4*)(Z + (long)src * 256))[lane];
  const float4 b = ((const float4*)(Z + (long)dst * 256))[lane];
  const float4 w = ((const float4*)w2)[lane];
  float s = a.x * b.x * w.x + a.y * b.y * w.y + a.z * b.z * w.z + a.w * b.w * w.w;
#pragma unroll
  for (int off = 32; off > 0; off >>= 1) s += __shfl_down(s, off);
  if (lane == 0) out[wid] = 1.0f / (1.0f + expf(-s));
}

extern "C" void kernel_launch(void* const* d_in, const int* in_sizes, int n_in,
                              void* d_out, int out_size, void* d_ws, size_t ws_size,
                              hipStream_t stream)
{
  const float* X   = (const float*)d_in[0];
  const float* adj = (const float*)d_in[1];
  const float* W   = (const float*)d_in[2];
  const float* W2  = (const float*)d_in[3];
  const int*   te  = (const int*)d_in[4];
  const int*   fe  = (const int*)d_in[5];

  const int E = in_sizes[4] / 2;

  float* ws = (float*)d_ws;
  float* P0 = ws;                      // also XW (dead before gemm_adj writes)
  float* P1 = ws + NM_;                // final Z
  unsigned short* X1 = (unsigned short*)(ws + 2 * NM_);
  unsigned short* X2 = X1 + NM_;
  unsigned short* WT = X2 + NM_;       // 0.5 MB
  // total ws: 2*NM*4 + 2*NM*2 + 0.5MB ~ 50.9 MB (same as R9-R11)

  dim3 b256(256);
  w_split<<<dim3(64), b256, 0, stream>>>(W, WT);
  gemm_xw<<<dim3(256), b256, 0, stream>>>(X, WT, P0);          // XW -> P0 space
  transpose_split<<<dim3(256, 4), b256, 0, stream>>>(P0, X1, X2);
  gemm_adj<<<dim3(512), dim3(512), 0, stream>>>(adj, X1, P0, P1);
  reduce_add<<<dim3(2048), b256, 0, stream>>>(P0, P1, NM_ / 4);
  const long nwaves = 2L * E;
  const int nblocks = (int)((nwaves + 3) / 4);
  edge_score<<<dim3(nblocks), b256, 0, stream>>>(P1, W2, te, fe, E, (float*)d_out);
}

// Round 14
// 631.886 us; speedup vs baseline: 2.1824x; 1.9983x over previous
//
#include <hip/hip_runtime.h>
#include <math.h>

// N=16384, IN=512, HID=256, E=262144.
// Z = adj @ (X@W) via fp16 split-2 MFMA (a=a1+a2, b=b1+b2; 3 products).
// R14: m97-faithful GEMM2 -- BOTH operands staged via global_load_lds
// (pure DMA, no register round-trip, no mid-loop vmcnt waits). adj goes to
// LDS as f32; the fp16 split happens AFTER ds_read, on the lgkmcnt-
// scheduled path. One __syncthreads per K-tile. A-LDS layout is row-major
// with a c-XOR swizzle applied via PRE-SWIZZLED SOURCE addresses (DMA dest
// must stay linear); B is fragment-ready fp16 (pre-split by transpose_split).

typedef _Float16 half8v __attribute__((ext_vector_type(8)));
typedef __fp16   fp16x2 __attribute__((ext_vector_type(2)));
typedef __attribute__((ext_vector_type(4))) float floatx4;

#define NM_ (16384L * 256L)
#define KT 256   // 32-wide k-tiles per split-K half

static __device__ __forceinline__ void split2_pair_f16(float x0, float x1,
                                                       unsigned& q1, unsigned& q2) {
  _Float16 h0 = (_Float16)x0, h1 = (_Float16)x1;
  float r0 = x0 - (float)h0, r1 = x1 - (float)h1;
  _Float16 g0 = (_Float16)r0, g1 = (_Float16)r1;
  q1 = ((unsigned)__builtin_bit_cast(unsigned short, h1) << 16) |
       __builtin_bit_cast(unsigned short, h0);
  q2 = ((unsigned)__builtin_bit_cast(unsigned short, g1) << 16) |
       __builtin_bit_cast(unsigned short, g0);
}

static __device__ __forceinline__ void split8(const float* __restrict__ x,
                                              half8v& a0, half8v& a1) {
  union U { unsigned u[4]; half8v h; } u0, u1;
#pragma unroll
  for (int p = 0; p < 4; ++p) {
    fp16x2 h = __builtin_amdgcn_cvt_pkrtz(x[2 * p], x[2 * p + 1]);
    float r0 = x[2 * p]     - (float)h[0];   // exact
    float r1 = x[2 * p + 1] - (float)h[1];
    fp16x2 g = __builtin_amdgcn_cvt_pkrtz(r0, r1);
    u0.u[p] = __builtin_bit_cast(unsigned, h);
    u1.u[p] = __builtin_bit_cast(unsigned, g);
  }
  a0 = u0.h; a1 = u1.h;
}

static __device__ __forceinline__ void gload_lds16(const void* g, void* l) {
  __builtin_amdgcn_global_load_lds(
      (const __attribute__((address_space(1))) unsigned*)g,
      (__attribute__((address_space(3))) unsigned*)l, 16, 0, 0);
}

// ---- W[512][256] -> fragment-ready split WT: [s][kt(16)][c(4)][n(256)][8] ----
__global__ __launch_bounds__(256)
void w_split(const float* __restrict__ W, unsigned short* __restrict__ WT)
{
  const int b  = blockIdx.x;          // 64 blocks
  const int kt = b >> 2, c = b & 3;
  const int n  = threadIdx.x;
  const int k0 = kt * 32 + c * 8;
  float x[8];
#pragma unroll
  for (int j = 0; j < 8; ++j) x[j] = W[(k0 + j) * 256 + n];
  unsigned q1[4], q2[4];
#pragma unroll
  for (int p = 0; p < 4; ++p)
    split2_pair_f16(x[2 * p], x[2 * p + 1], q1[p], q2[p]);
  const long o = ((long)(kt * 4 + c) * 256 + n) * 8;
  *(uint4*)&WT[o]          = make_uint4(q1[0], q1[1], q1[2], q1[3]);
  *(uint4*)&WT[o + 131072] = make_uint4(q2[0], q2[1], q2[2], q2[3]);
}

// ---- GEMM1: XW = X @ W, LDS-free fragment-direct, chunk-4 accS ----
__global__ __launch_bounds__(256, 2)
void gemm_xw(const float* __restrict__ X, const unsigned short* __restrict__ WT,
             float* __restrict__ XW)
{
  const int tid  = threadIdx.x;
  const int lane = tid & 63;
  const int w    = tid >> 6;
  const int wm = w >> 1, wn = w & 1;
  const long m0 = (long)(blockIdx.x >> 1) * 128;
  const long n0 = (long)(blockIdx.x & 1) * 128;
  const int fr = lane & 15, kc = lane >> 4;

  const unsigned short* Bq = WT + (long)kc * 2048 + ((long)n0 + wn * 64 + fr) * 8;

  const float* ap[4];
#pragma unroll
  for (int fm = 0; fm < 4; ++fm)
    ap[fm] = X + (m0 + wm * 64 + fm * 16 + fr) * 512L + kc * 8;

  floatx4 acc[4][4], accS[4][4];
#pragma unroll
  for (int i = 0; i < 4; ++i)
#pragma unroll
    for (int j = 0; j < 4; ++j) { acc[i][j] = (floatx4)0.f; accS[i][j] = (floatx4)0.f; }

  for (int t = 0; t < 16; ++t) {
    half8v bf0[4], bf1[4];
#pragma unroll
    for (int fn = 0; fn < 4; ++fn) {
      bf0[fn] = *(const half8v*)(Bq + (long)t * 8192 + fn * 128);
      bf1[fn] = *(const half8v*)(Bq + (long)t * 8192 + fn * 128 + 131072);
    }
#pragma unroll
    for (int fm = 0; fm < 4; ++fm) {
      float x[8];
      *(float4*)&x[0] = *(const float4*)(ap[fm] + t * 32);
      *(float4*)&x[4] = *(const float4*)(ap[fm] + t * 32 + 4);
      half8v a0, a1;
      split8(x, a0, a1);
#pragma unroll
      for (int fn = 0; fn < 4; ++fn) {
        floatx4 d = acc[fm][fn];
        d = __builtin_amdgcn_mfma_f32_16x16x32_f16(a0, bf0[fn], d, 0, 0, 0);
        d = __builtin_amdgcn_mfma_f32_16x16x32_f16(a0, bf1[fn], d, 0, 0, 0);
        d = __builtin_amdgcn_mfma_f32_16x16x32_f16(a1, bf0[fn], d, 0, 0, 0);
        acc[fm][fn] = d;
      }
    }
    if ((t & 3) == 3) {
#pragma unroll
      for (int i = 0; i < 4; ++i)
#pragma unroll
        for (int j = 0; j < 4; ++j) { accS[i][j] += acc[i][j]; acc[i][j] = (floatx4)0.f; }
    }
  }
#pragma unroll
  for (int fm = 0; fm < 4; ++fm)
#pragma unroll
    for (int fn = 0; fn < 4; ++fn) {
      const long col  = n0 + wn * 64 + fn * 16 + fr;
      const long rowb = m0 + wm * 64 + fm * 16 + kc * 4;
#pragma unroll
      for (int j = 0; j < 4; ++j)
        XW[(rowb + j) * 256 + col] = accS[fm][fn][j];
    }
}

// ---- transpose + split2 XW -> fragment-ready: [s][kt(512)][c(4)][n(256)][8] ----
__global__ __launch_bounds__(256)
void transpose_split(const float* __restrict__ XW,
                     unsigned short* __restrict__ X1,
                     unsigned short* __restrict__ X2)
{
  __shared__ float T[64][65];
  const int tid = threadIdx.x;
  const long kb = (long)blockIdx.x * 64;
  const long nb = (long)blockIdx.y * 64;

#pragma unroll
  for (int i = 0; i < 4; ++i) {
    int idx = tid + 256 * i;
    int r = idx >> 4, c4 = (idx & 15) * 4;
    float4 v = *(const float4*)&XW[(kb + r) * 256 + nb + c4];
    T[r][c4 + 0] = v.x; T[r][c4 + 1] = v.y; T[r][c4 + 2] = v.z; T[r][c4 + 3] = v.w;
  }
  __syncthreads();

#pragma unroll
  for (int i = 0; i < 2; ++i) {
    int idx = tid + 256 * i;
    int n = idx >> 3, kq = (idx & 7) * 8;
    float x[8];
#pragma unroll
    for (int j = 0; j < 8; ++j) x[j] = T[kq + j][n];
    unsigned q1[4], q2[4];
#pragma unroll
    for (int p = 0; p < 4; ++p)
      split2_pair_f16(x[2 * p], x[2 * p + 1], q1[p], q2[p]);
    const long gk = kb + kq;
    const long gt = gk >> 5;
    const int  c  = (int)((gk >> 3) & 3);
    const long o  = ((gt * 4 + c) * 256 + (nb + n)) * 8;
    *(uint4*)&X1[o] = make_uint4(q1[0], q1[1], q1[2], q1[3]);
    *(uint4*)&X2[o] = make_uint4(q2[0], q2[1], q2[2], q2[3]);
  }
}

// ---- GEMM2: Z-partials = adj @ XW. m97-style: all staging via gload_lds. ----
// 512 blocks x 256 thr (4 waves 2x2, wave=64x64). BM=128, BN=128, splitK=2.
// A in LDS as f32 [row(128)][4 chunk-slots x 32B], chunk slot XOR'd by row
// (c_stored_at_slot_s = (s>>1)^(row&3)) via pre-swizzled DMA source addrs.
// B in LDS as fp16 [sp][c][n(128)][8]. One __syncthreads per K-tile.
__global__ __launch_bounds__(256)
void gemm_adj(const float* __restrict__ A, const unsigned short* __restrict__ Bg,
              float* __restrict__ P0, float* __restrict__ P1)
{
  __shared__ float          As[2][4096];    // 2 x 16 KB (128 rows x 32 f32)
  __shared__ unsigned short Bs[2][8192];    // 2 x 16 KB (2sp x 4c x 128n x 8)

  const int tid  = threadIdx.x;
  const int lane = tid & 63;
  const int w    = tid >> 6;          // 0..3
  const int wm = w >> 1, wn = w & 1;

  // swizzle: j = xcd + 8*(n + 2*q); (m,z) from (q,xcd); n-pair 8 slots apart
  const int j   = blockIdx.x;
  const int xcd = j & 7;
  const int nh  = (j >> 3) & 1;
  const int q   = j >> 4;             // 0..31
  const int mz  = q * 8 + xcd;        // 0..255
  const long m0 = (long)(mz >> 1) * 128;
  const int  z  = mz & 1;
  const long n0 = (long)nh * 128;
  float* __restrict__ Cp = z ? P1 : P0;
  const int fr = lane & 15, kc = lane >> 4;

  // ---- A-DMA source (pre-swizzled): instr i=4w+qq, lane: slot jj=i*64+lane
  // r=jj>>3, s=jj&7, chunk c=(s>>1)^(r&3), half=s&1
  const float* AgQ[4];
#pragma unroll
  for (int qq = 0; qq < 4; ++qq) {
    const int jj = (4 * w + qq) * 64 + lane;
    const int r  = jj >> 3, s = jj & 7;
    const int c  = (s >> 1) ^ (r & 3);
    AgQ[qq] = A + (m0 + r) * 16384L + (long)z * 8192 + c * 8 + (s & 1) * 4;
  }
  // ---- B-DMA source: instr idx=4w+qq: sp=idx>>3, c=(idx>>1)&3, hf=idx&1
  const unsigned short* BgQ[4];
  int bLds[4];
#pragma unroll
  for (int qq = 0; qq < 4; ++qq) {
    const int idx = 4 * w + qq;
    const int sp = idx >> 3, c = (idx >> 1) & 3, hf = idx & 1;
    BgQ[qq] = Bg + (long)sp * NM_ + ((long)c * 256 + n0 + hf * 64 + lane) * 8;
    bLds[qq] = ((sp * 4 + c) * 128 + hf * 64) * 8;   // ushort units
  }

  // ---- fragment read offsets ----
  int aOff[4][2];   // f32 units: per fm, per half
#pragma unroll
  for (int fm = 0; fm < 4; ++fm) {
    const int R = wm * 64 + fm * 16 + fr;
#pragma unroll
    for (int h = 0; h < 2; ++h)
      aOff[fm][h] = R * 32 + ((kc ^ (fr & 3)) * 2 + h) * 4;
  }
  int bOff[4][2];   // ushort units: per fn, per sp
#pragma unroll
  for (int fn = 0; fn < 4; ++fn)
#pragma unroll
    for (int sp = 0; sp < 2; ++sp)
      bOff[fn][sp] = ((sp * 4 + kc) * 128 + wn * 64 + fn * 16 + fr) * 8;

  floatx4 acc[4][4], accS[4][4];
#pragma unroll
  for (int i = 0; i < 4; ++i)
#pragma unroll
    for (int jx = 0; jx < 4; ++jx) { acc[i][jx] = (floatx4)0.f; accS[i][jx] = (floatx4)0.f; }

#define STAGE(TT, BUF)                                                            \
  {                                                                               \
    const long koA = (long)((TT) & (KT - 1)) * 32;                                \
    const long koB = (long)((TT) & (KT - 1)) * 8192 + (long)z * 2097152;          \
    _Pragma("unroll")                                                             \
    for (int qq = 0; qq < 4; ++qq)                                                \
      gload_lds16(AgQ[qq] + koA, &As[BUF][(4 * w + qq) * 256]);                   \
    _Pragma("unroll")                                                             \
    for (int qq = 0; qq < 4; ++qq)                                                \
      gload_lds16(BgQ[qq] + koB, &Bs[BUF][bLds[qq]]);                             \
  }

  // prologue: stage tile 0
  STAGE(0, 0);
  __syncthreads();

  int buf = 0;
  for (int t = 0; t < KT; ++t) {
    STAGE(t + 1, buf ^ 1);    // pure DMA issue; lands during compute below
    __builtin_amdgcn_sched_barrier(0);
    // compute tile t
    half8v bf[2][4];
#pragma unroll
    for (int fn = 0; fn < 4; ++fn) {
      bf[0][fn] = *(const half8v*)&Bs[buf][bOff[fn][0]];
      bf[1][fn] = *(const half8v*)&Bs[buf][bOff[fn][1]];
    }
#pragma unroll
    for (int fm = 0; fm < 4; ++fm) {
      float x[8];
      *(float4*)&x[0] = *(const float4*)&As[buf][aOff[fm][0]];
      *(float4*)&x[4] = *(const float4*)&As[buf][aOff[fm][1]];
      half8v a0, a1;
      split8(x, a0, a1);
#pragma unroll
      for (int fn = 0; fn < 4; ++fn) {
        floatx4 d = acc[fm][fn];
        d = __builtin_amdgcn_mfma_f32_16x16x32_f16(a0, bf[0][fn], d, 0, 0, 0);
        d = __builtin_amdgcn_mfma_f32_16x16x32_f16(a0, bf[1][fn], d, 0, 0, 0);
        d = __builtin_amdgcn_mfma_f32_16x16x32_f16(a1, bf[0][fn], d, 0, 0, 0);
        acc[fm][fn] = d;
      }
    }
    if ((t & 31) == 31) {     // chunked accumulation (numerics, as R4-R13)
#pragma unroll
      for (int i = 0; i < 4; ++i)
#pragma unroll
        for (int jx = 0; jx < 4; ++jx) { accS[i][jx] += acc[i][jx]; acc[i][jx] = (floatx4)0.f; }
    }
    __syncthreads();          // drains DMA(t+1) + closes reads of buf
    buf ^= 1;
  }

  // epilogue: C/D layout col=lane&15, row=kc*4+jj
#pragma unroll
  for (int fm = 0; fm < 4; ++fm)
#pragma unroll
    for (int fn = 0; fn < 4; ++fn) {
      const long col  = n0 + wn * 64 + fn * 16 + fr;
      const long rowb = m0 + wm * 64 + fm * 16 + kc * 4;
#pragma unroll
      for (int jj = 0; jj < 4; ++jj)
        Cp[(rowb + jj) * 256 + col] = accS[fm][fn][jj];
    }
#undef STAGE
}

// ---------------- P1 += P0 ----------------
__global__ __launch_bounds__(256)
void reduce_add(const float* __restrict__ P0, float* __restrict__ P1, long n4)
{
  long i = (long)blockIdx.x * 256 + threadIdx.x;
  const long stride = (long)gridDim.x * 256;
  for (; i < n4; i += stride) {
    float4 a = ((const float4*)P0)[i];
    float4 b = ((const float4*)P1)[i];
    b.x += a.x; b.y += a.y; b.z += a.z; b.w += a.w;
    ((float4*)P1)[i] = b;
  }
}

// ---------------- edge scoring ----------------
__global__ __launch_bounds__(256)
void edge_score(const float* __restrict__ Z, const float* __restrict__ w2,
                const int* __restrict__ te, const int* __restrict__ fe,
                int E, float* __restrict__ out)
{
  const long gtid = (long)blockIdx.x * 256 + threadIdx.x;
  const long wid = gtid >> 6;
  const int lane = threadIdx.x & 63;
  if (wid >= 2L * E) return;
  const int* ep = (wid < E) ? (te + 2 * wid) : (fe + 2 * (wid - E));
  const int src = ep[0];
  const int dst = ep[1];
  const float4 a = ((const float4*)(Z + (long)src * 256))[lane];
  const float4 b = ((const float4*)(Z + (long)dst * 256))[lane];
  const float4 w = ((const float4*)w2)[lane];
  float s = a.x * b.x * w.x + a.y * b.y * w.y + a.z * b.z * w.z + a.w * b.w * w.w;
#pragma unroll
  for (int off = 32; off > 0; off >>= 1) s += __shfl_down(s, off);
  if (lane == 0) out[wid] = 1.0f / (1.0f + expf(-s));
}

extern "C" void kernel_launch(void* const* d_in, const int* in_sizes, int n_in,
                              void* d_out, int out_size, void* d_ws, size_t ws_size,
                              hipStream_t stream)
{
  const float* X   = (const float*)d_in[0];
  const float* adj = (const float*)d_in[1];
  const float* W   = (const float*)d_in[2];
  const float* W2  = (const float*)d_in[3];
  const int*   te  = (const int*)d_in[4];
  const int*   fe  = (const int*)d_in[5];

  const int E = in_sizes[4] / 2;

  float* ws = (float*)d_ws;
  float* P0 = ws;                      // also XW (dead before gemm_adj writes)
  float* P1 = ws + NM_;                // final Z
  unsigned short* X1 = (unsigned short*)(ws + 2 * NM_);
  unsigned short* X2 = X1 + NM_;
  unsigned short* WT = X2 + NM_;       // 0.5 MB
  // total ws: 2*NM*4 + 2*NM*2 + 0.5MB ~ 50.9 MB

  dim3 b256(256);
  w_split<<<dim3(64), b256, 0, stream>>>(W, WT);
  gemm_xw<<<dim3(256), b256, 0, stream>>>(X, WT, P0);          // XW -> P0 space
  transpose_split<<<dim3(256, 4), b256, 0, stream>>>(P0, X1, X2);
  gemm_adj<<<dim3(512), b256, 0, stream>>>(adj, X1, P0, P1);
  reduce_add<<<dim3(2048), b256, 0, stream>>>(P0, P1, NM_ / 4);
  const long nwaves = 2L * E;
  const int nblocks = (int)((nwaves + 3) / 4);
  edge_score<<<dim3(nblocks), b256, 0, stream>>>(P1, W2, te, fe, E, (float*)d_out);
}

// Round 15
// 620.504 us; speedup vs baseline: 2.2224x; 1.0183x over previous
//
#include <hip/hip_runtime.h>
#include <math.h>

// N=16384, IN=512, HID=256, E=262144.
// Z = adj @ (X@W) via fp16 split-2 MFMA (a=a1+a2, b=b1+b2; 3 products).
// R14 core (kept byte-identical): gemm_adj stages BOTH operands via
// global_load_lds (pure DMA, no mid-loop waits), fp16 split AFTER ds_read,
// one __syncthreads per K-tile, A-LDS c-XOR swizzle via pre-swizzled DMA
// source. R15: transpose_split kernel ELIMINATED -- gemm_xw's epilogue
// writes the split fragments directly to X1/X2 (addr = (k>>3)*2048+n*8+(k&7),
// constant over a lane's 4 consecutive k; aligned 8B stores).

typedef _Float16 half8v __attribute__((ext_vector_type(8)));
typedef __fp16   fp16x2 __attribute__((ext_vector_type(2)));
typedef __attribute__((ext_vector_type(4))) float floatx4;

#define NM_ (16384L * 256L)
#define KT 256   // 32-wide k-tiles per split-K half

static __device__ __forceinline__ void split2_pair_f16(float x0, float x1,
                                                       unsigned& q1, unsigned& q2) {
  _Float16 h0 = (_Float16)x0, h1 = (_Float16)x1;
  float r0 = x0 - (float)h0, r1 = x1 - (float)h1;
  _Float16 g0 = (_Float16)r0, g1 = (_Float16)r1;
  q1 = ((unsigned)__builtin_bit_cast(unsigned short, h1) << 16) |
       __builtin_bit_cast(unsigned short, h0);
  q2 = ((unsigned)__builtin_bit_cast(unsigned short, g1) << 16) |
       __builtin_bit_cast(unsigned short, g0);
}

static __device__ __forceinline__ void split8(const float* __restrict__ x,
                                              half8v& a0, half8v& a1) {
  union U { unsigned u[4]; half8v h; } u0, u1;
#pragma unroll
  for (int p = 0; p < 4; ++p) {
    fp16x2 h = __builtin_amdgcn_cvt_pkrtz(x[2 * p], x[2 * p + 1]);
    float r0 = x[2 * p]     - (float)h[0];   // exact
    float r1 = x[2 * p + 1] - (float)h[1];
    fp16x2 g = __builtin_amdgcn_cvt_pkrtz(r0, r1);
    u0.u[p] = __builtin_bit_cast(unsigned, h);
    u1.u[p] = __builtin_bit_cast(unsigned, g);
  }
  a0 = u0.h; a1 = u1.h;
}

static __device__ __forceinline__ void gload_lds16(const void* g, void* l) {
  __builtin_amdgcn_global_load_lds(
      (const __attribute__((address_space(1))) unsigned*)g,
      (__attribute__((address_space(3))) unsigned*)l, 16, 0, 0);
}

// ---- W[512][256] -> fragment-ready split WT: [s][kt(16)][c(4)][n(256)][8] ----
__global__ __launch_bounds__(256)
void w_split(const float* __restrict__ W, unsigned short* __restrict__ WT)
{
  const int b  = blockIdx.x;          // 64 blocks
  const int kt = b >> 2, c = b & 3;
  const int n  = threadIdx.x;
  const int k0 = kt * 32 + c * 8;
  float x[8];
#pragma unroll
  for (int j = 0; j < 8; ++j) x[j] = W[(k0 + j) * 256 + n];
  unsigned q1[4], q2[4];
#pragma unroll
  for (int p = 0; p < 4; ++p)
    split2_pair_f16(x[2 * p], x[2 * p + 1], q1[p], q2[p]);
  const long o = ((long)(kt * 4 + c) * 256 + n) * 8;
  *(uint4*)&WT[o]          = make_uint4(q1[0], q1[1], q1[2], q1[3]);
  *(uint4*)&WT[o + 131072] = make_uint4(q2[0], q2[1], q2[2], q2[3]);
}

// ---- GEMM1: XW = X @ W; epilogue writes split fragments directly ----
__global__ __launch_bounds__(256, 2)
void gemm_xw(const float* __restrict__ X, const unsigned short* __restrict__ WT,
             unsigned short* __restrict__ X1, unsigned short* __restrict__ X2)
{
  const int tid  = threadIdx.x;
  const int lane = tid & 63;
  const int w    = tid >> 6;
  const int wm = w >> 1, wn = w & 1;
  const long m0 = (long)(blockIdx.x >> 1) * 128;
  const long n0 = (long)(blockIdx.x & 1) * 128;
  const int fr = lane & 15, kc = lane >> 4;

  const unsigned short* Bq = WT + (long)kc * 2048 + ((long)n0 + wn * 64 + fr) * 8;

  const float* ap[4];
#pragma unroll
  for (int fm = 0; fm < 4; ++fm)
    ap[fm] = X + (m0 + wm * 64 + fm * 16 + fr) * 512L + kc * 8;

  floatx4 acc[4][4], accS[4][4];
#pragma unroll
  for (int i = 0; i < 4; ++i)
#pragma unroll
    for (int j = 0; j < 4; ++j) { acc[i][j] = (floatx4)0.f; accS[i][j] = (floatx4)0.f; }

  for (int t = 0; t < 16; ++t) {
    half8v bf0[4], bf1[4];
#pragma unroll
    for (int fn = 0; fn < 4; ++fn) {
      bf0[fn] = *(const half8v*)(Bq + (long)t * 8192 + fn * 128);
      bf1[fn] = *(const half8v*)(Bq + (long)t * 8192 + fn * 128 + 131072);
    }
#pragma unroll
    for (int fm = 0; fm < 4; ++fm) {
      float x[8];
      *(float4*)&x[0] = *(const float4*)(ap[fm] + t * 32);
      *(float4*)&x[4] = *(const float4*)(ap[fm] + t * 32 + 4);
      half8v a0, a1;
      split8(x, a0, a1);
#pragma unroll
      for (int fn = 0; fn < 4; ++fn) {
        floatx4 d = acc[fm][fn];
        d = __builtin_amdgcn_mfma_f32_16x16x32_f16(a0, bf0[fn], d, 0, 0, 0);
        d = __builtin_amdgcn_mfma_f32_16x16x32_f16(a0, bf1[fn], d, 0, 0, 0);
        d = __builtin_amdgcn_mfma_f32_16x16x32_f16(a1, bf0[fn], d, 0, 0, 0);
        acc[fm][fn] = d;
      }
    }
    if ((t & 3) == 3) {
#pragma unroll
      for (int i = 0; i < 4; ++i)
#pragma unroll
        for (int j = 0; j < 4; ++j) { accS[i][j] += acc[i][j]; acc[i][j] = (floatx4)0.f; }
    }
  }

  // epilogue: direct fragment-ready split write.
  // XW element (k=row, n=col) lives at (k>>3)*2048 + n*8 + (k&7) ushorts;
  // a lane's 4 k are consecutive with K0 % 4 == 0 -> one aligned 8B store
  // per (fragment, split).
#pragma unroll
  for (int fm = 0; fm < 4; ++fm) {
    const long K0 = m0 + wm * 64 + fm * 16 + kc * 4;
    const long kb = (K0 >> 3) * 2048 + (K0 & 7);
#pragma unroll
    for (int fn = 0; fn < 4; ++fn) {
      const long n = n0 + wn * 64 + fn * 16 + fr;
      unsigned short h4[4], g4[4];
#pragma unroll
      for (int j = 0; j < 4; ++j) {
        float v = accS[fm][fn][j];
        _Float16 h = (_Float16)v;          // RNE
        float r = v - (float)h;            // exact
        _Float16 g = (_Float16)r;
        h4[j] = __builtin_bit_cast(unsigned short, h);
        g4[j] = __builtin_bit_cast(unsigned short, g);
      }
      const long o = kb + n * 8;
      *(uint2*)&X1[o] = *(uint2*)h4;
      *(uint2*)&X2[o] = *(uint2*)g4;
    }
  }
}

// ---- GEMM2: Z-partials = adj @ XW. m97-style: all staging via gload_lds. ----
// 512 blocks x 256 thr (4 waves 2x2, wave=64x64). BM=128, BN=128, splitK=2.
// (byte-identical to R14 -- validated at ~900-1080 TF effective)
__global__ __launch_bounds__(256)
void gemm_adj(const float* __restrict__ A, const unsigned short* __restrict__ Bg,
              float* __restrict__ P0, float* __restrict__ P1)
{
  __shared__ float          As[2][4096];    // 2 x 16 KB (128 rows x 32 f32)
  __shared__ unsigned short Bs[2][8192];    // 2 x 16 KB (2sp x 4c x 128n x 8)

  const int tid  = threadIdx.x;
  const int lane = tid & 63;
  const int w    = tid >> 6;          // 0..3
  const int wm = w >> 1, wn = w & 1;

  const int j   = blockIdx.x;
  const int xcd = j & 7;
  const int nh  = (j >> 3) & 1;
  const int q   = j >> 4;             // 0..31
  const int mz  = q * 8 + xcd;        // 0..255
  const long m0 = (long)(mz >> 1) * 128;
  const int  z  = mz & 1;
  const long n0 = (long)nh * 128;
  float* __restrict__ Cp = z ? P1 : P0;
  const int fr = lane & 15, kc = lane >> 4;

  const float* AgQ[4];
#pragma unroll
  for (int qq = 0; qq < 4; ++qq) {
    const int jj = (4 * w + qq) * 64 + lane;
    const int r  = jj >> 3, s = jj & 7;
    const int c  = (s >> 1) ^ (r & 3);
    AgQ[qq] = A + (m0 + r) * 16384L + (long)z * 8192 + c * 8 + (s & 1) * 4;
  }
  const unsigned short* BgQ[4];
  int bLds[4];
#pragma unroll
  for (int qq = 0; qq < 4; ++qq) {
    const int idx = 4 * w + qq;
    const int sp = idx >> 3, c = (idx >> 1) & 3, hf = idx & 1;
    BgQ[qq] = Bg + (long)sp * NM_ + ((long)c * 256 + n0 + hf * 64 + lane) * 8;
    bLds[qq] = ((sp * 4 + c) * 128 + hf * 64) * 8;
  }

  int aOff[4][2];
#pragma unroll
  for (int fm = 0; fm < 4; ++fm) {
    const int R = wm * 64 + fm * 16 + fr;
#pragma unroll
    for (int h = 0; h < 2; ++h)
      aOff[fm][h] = R * 32 + ((kc ^ (fr & 3)) * 2 + h) * 4;
  }
  int bOff[4][2];
#pragma unroll
  for (int fn = 0; fn < 4; ++fn)
#pragma unroll
    for (int sp = 0; sp < 2; ++sp)
      bOff[fn][sp] = ((sp * 4 + kc) * 128 + wn * 64 + fn * 16 + fr) * 8;

  floatx4 acc[4][4], accS[4][4];
#pragma unroll
  for (int i = 0; i < 4; ++i)
#pragma unroll
    for (int jx = 0; jx < 4; ++jx) { acc[i][jx] = (floatx4)0.f; accS[i][jx] = (floatx4)0.f; }

#define STAGE(TT, BUF)                                                            \
  {                                                                               \
    const long koA = (long)((TT) & (KT - 1)) * 32;                                \
    const long koB = (long)((TT) & (KT - 1)) * 8192 + (long)z * 2097152;          \
    _Pragma("unroll")                                                             \
    for (int qq = 0; qq < 4; ++qq)                                                \
      gload_lds16(AgQ[qq] + koA, &As[BUF][(4 * w + qq) * 256]);                   \
    _Pragma("unroll")                                                             \
    for (int qq = 0; qq < 4; ++qq)                                                \
      gload_lds16(BgQ[qq] + koB, &Bs[BUF][bLds[qq]]);                             \
  }

  STAGE(0, 0);
  __syncthreads();

  int buf = 0;
  for (int t = 0; t < KT; ++t) {
    STAGE(t + 1, buf ^ 1);
    __builtin_amdgcn_sched_barrier(0);
    half8v bf[2][4];
#pragma unroll
    for (int fn = 0; fn < 4; ++fn) {
      bf[0][fn] = *(const half8v*)&Bs[buf][bOff[fn][0]];
      bf[1][fn] = *(const half8v*)&Bs[buf][bOff[fn][1]];
    }
#pragma unroll
    for (int fm = 0; fm < 4; ++fm) {
      float x[8];
      *(float4*)&x[0] = *(const float4*)&As[buf][aOff[fm][0]];
      *(float4*)&x[4] = *(const float4*)&As[buf][aOff[fm][1]];
      half8v a0, a1;
      split8(x, a0, a1);
#pragma unroll
      for (int fn = 0; fn < 4; ++fn) {
        floatx4 d = acc[fm][fn];
        d = __builtin_amdgcn_mfma_f32_16x16x32_f16(a0, bf[0][fn], d, 0, 0, 0);
        d = __builtin_amdgcn_mfma_f32_16x16x32_f16(a0, bf[1][fn], d, 0, 0, 0);
        d = __builtin_amdgcn_mfma_f32_16x16x32_f16(a1, bf[0][fn], d, 0, 0, 0);
        acc[fm][fn] = d;
      }
    }
    if ((t & 31) == 31) {
#pragma unroll
      for (int i = 0; i < 4; ++i)
#pragma unroll
        for (int jx = 0; jx < 4; ++jx) { accS[i][jx] += acc[i][jx]; acc[i][jx] = (floatx4)0.f; }
    }
    __syncthreads();
    buf ^= 1;
  }

#pragma unroll
  for (int fm = 0; fm < 4; ++fm)
#pragma unroll
    for (int fn = 0; fn < 4; ++fn) {
      const long col  = n0 + wn * 64 + fn * 16 + fr;
      const long rowb = m0 + wm * 64 + fm * 16 + kc * 4;
#pragma unroll
      for (int jj = 0; jj < 4; ++jj)
        Cp[(rowb + jj) * 256 + col] = accS[fm][fn][jj];
    }
#undef STAGE
}

// ---------------- P1 += P0 ----------------
__global__ __launch_bounds__(256)
void reduce_add(const float* __restrict__ P0, float* __restrict__ P1, long n4)
{
  long i = (long)blockIdx.x * 256 + threadIdx.x;
  const long stride = (long)gridDim.x * 256;
  for (; i < n4; i += stride) {
    float4 a = ((const float4*)P0)[i];
    float4 b = ((const float4*)P1)[i];
    b.x += a.x; b.y += a.y; b.z += a.z; b.w += a.w;
    ((float4*)P1)[i] = b;
  }
}

// ---------------- edge scoring ----------------
__global__ __launch_bounds__(256)
void edge_score(const float* __restrict__ Z, const float* __restrict__ w2,
                const int* __restrict__ te, const int* __restrict__ fe,
                int E, float* __restrict__ out)
{
  const long gtid = (long)blockIdx.x * 256 + threadIdx.x;
  const long wid = gtid >> 6;
  const int lane = threadIdx.x & 63;
  if (wid >= 2L * E) return;
  const int* ep = (wid < E) ? (te + 2 * wid) : (fe + 2 * (wid - E));
  const int src = ep[0];
  const int dst = ep[1];
  const float4 a = ((const float4*)(Z + (long)src * 256))[lane];
  const float4 b = ((const float4*)(Z + (long)dst * 256))[lane];
  const float4 w = ((const float4*)w2)[lane];
  float s = a.x * b.x * w.x + a.y * b.y * w.y + a.z * b.z * w.z + a.w * b.w * w.w;
#pragma unroll
  for (int off = 32; off > 0; off >>= 1) s += __shfl_down(s, off);
  if (lane == 0) out[wid] = 1.0f / (1.0f + expf(-s));
}

extern "C" void kernel_launch(void* const* d_in, const int* in_sizes, int n_in,
                              void* d_out, int out_size, void* d_ws, size_t ws_size,
                              hipStream_t stream)
{
  const float* X   = (const float*)d_in[0];
  const float* adj = (const float*)d_in[1];
  const float* W   = (const float*)d_in[2];
  const float* W2  = (const float*)d_in[3];
  const int*   te  = (const int*)d_in[4];
  const int*   fe  = (const int*)d_in[5];

  const int E = in_sizes[4] / 2;

  float* ws = (float*)d_ws;
  float* P0 = ws;                      // split-K partial 0
  float* P1 = ws + NM_;                // final Z
  unsigned short* X1 = (unsigned short*)(ws + 2 * NM_);
  unsigned short* X2 = X1 + NM_;
  unsigned short* WT = X2 + NM_;       // 0.5 MB
  // total ws: 2*NM*4 + 2*NM*2 + 0.5MB ~ 50.9 MB

  dim3 b256(256);
  w_split<<<dim3(64), b256, 0, stream>>>(W, WT);
  gemm_xw<<<dim3(256), b256, 0, stream>>>(X, WT, X1, X2);   // fragments direct
  gemm_adj<<<dim3(512), b256, 0, stream>>>(adj, X1, P0, P1);
  reduce_add<<<dim3(2048), b256, 0, stream>>>(P0, P1, NM_ / 4);
  const long nwaves = 2L * E;
  const int nblocks = (int)((nwaves + 3) / 4);
  edge_score<<<dim3(nblocks), b256, 0, stream>>>(P1, W2, te, fe, E, (float*)d_out);
}